// Round 18
// baseline (340.791 us; speedup 1.0000x reference)
//
#include <hip/hip_runtime.h>
#include <hip/hip_bf16.h>
#include <math.h>

#define BB 32
#define NN 512
#define TT 24
#define CC 64
#define CT 1536   // CC*TT
#define YD 3624   // 151*TT
#define YP 3648   // YD padded to 114*32 (= 57*64)

typedef __attribute__((ext_vector_type(4))) float f32x4;
typedef __attribute__((ext_vector_type(8))) short bf16x8;

static __device__ __forceinline__ short f2bf(float f){
  union { float f; unsigned u; } v; v.f = f;
  unsigned r = (v.u + 0x7FFF + ((v.u >> 16) & 1)) >> 16;
  return (short)r;
}
static __device__ __forceinline__ float bf2f(short s){
  union { unsigned u; float f; } v; v.u = ((unsigned)(unsigned short)s) << 16;
  return v.f;
}

// ---------------- fused preprocessing:
// [0,256) convS | [256,313) pad(y) | [313,3049) pad(tl_w) | [3049,3817) chebT
// [3817,3849) xT | [3849,6153) convW(l1_w) | [6153,6409) sbT | 6409: prep0
__global__ __launch_bounds__(256) void k_pre(const float* __restrict__ s_vs, const float* __restrict__ y,
                    const float* __restrict__ tl_w, const float* __restrict__ cheb,
                    const float* __restrict__ x, const float* __restrict__ l1_w,
                    const float* __restrict__ s_bs,
                    const float* __restrict__ u0_w, const float* __restrict__ u0_b,
                    const float* __restrict__ u1a, const float* __restrict__ u3a,
                    const float* __restrict__ u1b,
                    __hip_bfloat16* __restrict__ svB, __hip_bfloat16* __restrict__ yB,
                    __hip_bfloat16* __restrict__ WB, short* __restrict__ chT,
                    short* __restrict__ xTb, __hip_bfloat16* __restrict__ Wb,
                    float* __restrict__ sbT,
                    float* __restrict__ w0u3, float* __restrict__ b0u3, float* __restrict__ sums){
  __shared__ float shm[512*25];
  int bb = blockIdx.x, tid = threadIdx.x;
  if (bb < 256){
    int i = (bb*256 + tid)*4;
    float4 v = *(const float4*)(s_vs + i);
    svB[i+0] = __float2bfloat16(v.x);
    svB[i+1] = __float2bfloat16(v.y);
    svB[i+2] = __float2bfloat16(v.z);
    svB[i+3] = __float2bfloat16(v.w);
  } else if (bb < 313){
    int gid = (bb - 256)*256 + tid;
    int r = gid / (YP/8), c8 = (gid % (YP/8))*8;
    if (r < 32){
      bf16x8 o;
      if (c8 < YD){
        float4 a = *(const float4*)(y + (size_t)r*YD + c8);
        float4 b = *(const float4*)(y + (size_t)r*YD + c8 + 4);
        o[0]=f2bf(a.x); o[1]=f2bf(a.y); o[2]=f2bf(a.z); o[3]=f2bf(a.w);
        o[4]=f2bf(b.x); o[5]=f2bf(b.y); o[6]=f2bf(b.z); o[7]=f2bf(b.w);
      } else {
        for (int j = 0; j < 8; ++j) o[j] = 0;
      }
      *(bf16x8*)((short*)yB + (size_t)r*YP + c8) = o;
    }
  } else if (bb < 3049){
    int gid = (bb - 313)*256 + tid;
    int r = gid / (YP/8), c8 = (gid % (YP/8))*8;
    if (r < 1536){
      bf16x8 o;
      if (c8 < YD){
        float4 a = *(const float4*)(tl_w + (size_t)r*YD + c8);
        float4 b = *(const float4*)(tl_w + (size_t)r*YD + c8 + 4);
        o[0]=f2bf(a.x); o[1]=f2bf(a.y); o[2]=f2bf(a.z); o[3]=f2bf(a.w);
        o[4]=f2bf(b.x); o[5]=f2bf(b.y); o[6]=f2bf(b.z); o[7]=f2bf(b.w);
      } else {
        for (int j = 0; j < 8; ++j) o[j] = 0;
      }
      *(bf16x8*)((short*)WB + (size_t)r*YP + c8) = o;
    }
  } else if (bb < 3817){
    int q = bb - 3049;
    int jt = q & 15, it = (q >> 4) & 15, k = q >> 8;
    float (*ts)[33] = (float(*)[33])shm;
    int c = tid & 31, r8 = tid >> 5;
    #pragma unroll
    for (int p = 0; p < 4; ++p){
      int r = p*8 + r8;
      ts[r][c] = cheb[((size_t)k*NN + jt*32 + r)*NN + it*32 + c];
    }
    __syncthreads();
    #pragma unroll
    for (int p = 0; p < 4; ++p){
      int r = p*8 + r8;
      chT[((size_t)k*NN + it*32 + r)*NN + jt*32 + c] = f2bf(ts[c][r]);
    }
  } else if (bb < 3849){
    int b = bb - 3817;
    for (int idx = tid; idx < NN*TT; idx += 256){
      int j = idx / TT, t = idx % TT;
      shm[j*25 + t] = x[(size_t)b*NN*TT + idx];
    }
    __syncthreads();
    for (int u = tid; u < 32*64; u += 256){
      int t = u >> 6, j8 = (u & 63)*8;
      bf16x8 o;
      if (t < TT){
        #pragma unroll
        for (int e = 0; e < 8; ++e) o[e] = f2bf(shm[(j8 + e)*25 + t]);
      } else {
        #pragma unroll
        for (int e = 0; e < 8; ++e) o[e] = 0;
      }
      *(bf16x8*)(xTb + ((size_t)b*32 + t)*NN + j8) = o;
    }
  } else if (bb < 6153){
    int i = ((bb - 3849)*256 + tid)*4;
    float4 v = *(const float4*)(l1_w + i);
    Wb[i+0] = __float2bfloat16(v.x);
    Wb[i+1] = __float2bfloat16(v.y);
    Wb[i+2] = __float2bfloat16(v.z);
    Wb[i+3] = __float2bfloat16(v.w);
  } else if (bb < 6409){
    int q = bb - 6153;
    int mt = q & 15, kt = q >> 4;
    float (*ts)[33] = (float(*)[33])shm;
    int c = tid & 31, r8 = tid >> 5;
    #pragma unroll
    for (int p = 0; p < 4; ++p){
      int r = p*8 + r8;
      ts[r][c] = s_bs[(size_t)(mt*32 + r)*NN + kt*32 + c];
    }
    __syncthreads();
    #pragma unroll
    for (int p = 0; p < 4; ++p){
      int r = p*8 + r8;
      sbT[(size_t)(kt*32 + r)*NN + mt*32 + c] = ts[c][r];
    }
  } else {
    for (int e = tid; e < 576; e += 256){
      int tp = e / TT, t = e % TT;
      float acc = 0.f;
      for (int f = 0; f < CC; ++f) acc += u3a[f]*u0_w[(f*TT + tp)*TT + t];
      w0u3[e] = acc;
    }
    if (tid >= 64 && tid < 64 + TT){
      int t = tid - 64;
      float acc = 0.f;
      for (int f = 0; f < CC; ++f) acc += u3a[f]*u0_b[f*TT + t];
      b0u3[t] = acc;
    }
    if (tid == 0){ float s = 0.f; for (int n = 0; n < NN; ++n) s += u1a[n]; sums[0] = s; }
    if (tid == 1){ float s = 0.f; for (int n = 0; n < NN; ++n) s += u1b[n]; sums[1] = s; }
  }
}

// ---------------- pdt[ks][32][1536] = y-slice @ tl_w-slice^T  (MFMA, M=32, BK=64 + XOR swizzle)
__global__ __launch_bounds__(256) void k_dtgemm(const __hip_bfloat16* __restrict__ yB,
                       const __hip_bfloat16* __restrict__ WB, float* __restrict__ pdt){
  __shared__ __align__(16) short lA[32*64];
  __shared__ __align__(16) short lB[256*64];
  int nt = blockIdx.x, ks = blockIdx.y;
  int o0 = nt*256;
  int tid = threadIdx.x;
  int w = tid >> 6, l = tid & 63;
  int lrow = l & 15, lk = l >> 4;
  int srow = l >> 3;
  int scol = ((l & 7) ^ srow)*8;
  int swz = (lrow & 7) << 3;
  f32x4 acc[2][4];
  #pragma unroll
  for (int m = 0; m < 2; ++m)
    #pragma unroll
    for (int n = 0; n < 4; ++n) acc[m][n] = (f32x4){0.f,0.f,0.f,0.f};
  for (int step = 0; step < 3; ++step){
    int k0 = (ks*3 + step)*64;
    #pragma unroll
    for (int p = 0; p < 8; ++p){
      int c = p*4 + w;                 // 32 chunks: rows c*8..c*8+7 of 256x64 tile
      __builtin_amdgcn_global_load_lds(
        (const __attribute__((address_space(1))) void*)((const short*)WB + (size_t)(o0 + c*8 + srow)*YP + k0 + scol),
        (__attribute__((address_space(3))) void*)(lB + c*512), 16, 0, 0);
    }
    {
      int c = w;                       // 4 chunks cover 32 rows x 64 cols
      __builtin_amdgcn_global_load_lds(
        (const __attribute__((address_space(1))) void*)((const short*)yB + (size_t)(c*8 + srow)*YP + k0 + scol),
        (__attribute__((address_space(3))) void*)(lA + c*512), 16, 0, 0);
    }
    __syncthreads();
    #pragma unroll
    for (int h = 0; h < 2; ++h){
      bf16x8 a[2], bv[4];
      #pragma unroll
      for (int m = 0; m < 2; ++m){
        int row = m*16 + lrow;
        a[m] = *(const bf16x8*)(lA + row*64 + ((h*32 + lk*8) ^ swz));
      }
      #pragma unroll
      for (int n = 0; n < 4; ++n){
        int row = w*64 + n*16 + lrow;
        bv[n] = *(const bf16x8*)(lB + row*64 + ((h*32 + lk*8) ^ swz));
      }
      #pragma unroll
      for (int m = 0; m < 2; ++m)
        #pragma unroll
        for (int n = 0; n < 4; ++n)
          acc[m][n] = __builtin_amdgcn_mfma_f32_16x16x32_bf16(a[m], bv[n], acc[m][n], 0, 0, 0);
    }
    __syncthreads();
  }
  #pragma unroll
  for (int m = 0; m < 2; ++m){
    #pragma unroll
    for (int n = 0; n < 4; ++n){
      int o = o0 + w*64 + n*16 + lrow;
      #pragma unroll
      for (int j = 0; j < 4; ++j){
        int b = m*16 + lk*4 + j;
        pdt[((size_t)(ks*32 + b))*CT + o] = acc[m][n][j];
      }
    }
  }
}

// ---------------- per-b: dt reduce + xu, du3a, du3b, w1a
__global__ void k_small(const float* __restrict__ x, const float* __restrict__ pdt,
                        const float* __restrict__ tl_b,
                        const float* __restrict__ u0_w, const float* __restrict__ u0_b,
                        const float* __restrict__ u1a, const float* __restrict__ u3a,
                        const float* __restrict__ u3b, const float* __restrict__ sums,
                        float* __restrict__ dt,
                        float* __restrict__ w1a, float* __restrict__ du3a, float* __restrict__ du3b){
  __shared__ float xu_s[TT], u1a_s[NN], dt_s[CT];
  int b = blockIdx.x, tid = threadIdx.x;
  for (int o = tid; o < CT; o += 256){
    float acc = tl_b[o];
    #pragma unroll
    for (int ks = 0; ks < 19; ++ks) acc += pdt[((size_t)(ks*32 + b))*CT + o];
    dt_s[o] = acc;
    dt[b*CT + o] = acc;
  }
  for (int i = tid; i < NN; i += 256) u1a_s[i] = u1a[i];
  __syncthreads();
  int wv = tid >> 6, ln = tid & 63;
  for (int t = wv; t < TT; t += 4){
    float acc = 0.f;
    for (int n = ln; n < NN; n += 64) acc += u1a_s[n]*x[(size_t)(b*NN + n)*TT + t];
    for (int off = 32; off; off >>= 1) acc += __shfl_down(acc, off);
    if (ln == 0) xu_s[t] = acc;
  }
  if (tid < TT){
    float a = 0.f, c = 0.f;
    for (int f = 0; f < CC; ++f){
      float d = dt_s[tid*CC + f];
      a += u3a[f]*d; c += u3b[f]*d;
    }
    du3a[b*TT + tid] = a;
    du3b[b*TT + tid] = c;
  }
  __syncthreads();
  float S1 = sums[0];
  for (int idx = tid; idx < CC*TT; idx += 256){
    int f = idx / TT, tp = idx % TT;
    float acc = 0.f;
    const float* wrow = u0_w + (f*TT + tp)*TT;
    for (int t = 0; t < TT; ++t) acc += wrow[t]*xu_s[t];
    w1a[b*CC*TT + idx] = acc + S1*(u0_b[f*TT + tp] + dt_s[tp*CC + f]);
  }
}

// ---------------- att1 fused: rh inline from x/w0u3, lh from u2/w1, partial product
__global__ __launch_bounds__(576) void k_prodA(const float* __restrict__ x, const float* __restrict__ w0u3,
                      const float* __restrict__ b0u3, const float* __restrict__ du3a,
                      const float* __restrict__ u2, const float* __restrict__ w1,
                      float* __restrict__ pprod){
  __shared__ float u2s[64][65], w1s[CC*TT], lh[TT][64], rh[64][TT], xs[64*TT], w0_s[576], bd_s[TT];
  int ns = blockIdx.x, b = blockIdx.y;
  int n0 = ns*64, tid = threadIdx.x;
  for (int i = tid; i < 4096; i += 576){ int f = i >> 6, n = i & 63; u2s[f][n] = u2[f*NN + n0 + n]; }
  for (int i = tid; i < CC*TT; i += 576) w1s[i] = w1[b*CC*TT + i];
  for (int i = tid; i < 1536; i += 576) xs[i] = x[(size_t)(b*NN + n0)*TT + i];
  w0_s[tid] = w0u3[tid];
  if (tid < TT) bd_s[tid] = b0u3[tid] + du3a[b*TT + tid];
  __syncthreads();
  for (int idx = tid; idx < 1536; idx += 576){
    int n = idx / TT, tp = idx % TT;
    float acc = bd_s[tp];
    const float* wr = w0_s + tp*TT;
    const float* xr = xs + n*TT;
    #pragma unroll
    for (int t = 0; t < TT; ++t) acc += wr[t]*xr[t];
    rh[n][tp] = acc;
  }
  for (int idx = tid; idx < 1536; idx += 576){
    int t = idx >> 6, n = idx & 63;
    float acc = 0.f;
    #pragma unroll 8
    for (int f = 0; f < CC; ++f) acc += u2s[f][n]*w1s[f*TT + t];
    lh[t][n] = acc;
  }
  __syncthreads();
  int t = tid / TT, s = tid % TT;
  float acc = 0.f;
  #pragma unroll 4
  for (int n = 0; n < 64; ++n) acc += lh[t][n]*rh[n][s];
  pprod[((size_t)(b*8 + ns))*576 + tid] = acc;
}

// ---------------- att2: lhs+prod fused, w1 built inline from pw1g partials + S2*dt
__global__ __launch_bounds__(576) void k_prodB(const float* __restrict__ u2, const float* __restrict__ pw1g,
                      const float* __restrict__ dt, const float* __restrict__ sums,
                      const float* __restrict__ rhs, float* __restrict__ pprod){
  __shared__ float u2s[64][65], w1s[CC*TT], lh[TT][64], rh[64][TT];
  int ns = blockIdx.x, b = blockIdx.y;
  int n0 = ns*64, tid = threadIdx.x;
  for (int i = tid; i < 4096; i += 576){ int f = i >> 6, n = i & 63; u2s[f][n] = u2[f*NN + n0 + n]; }
  float S2 = sums[1];
  for (int i = tid; i < CC*TT; i += 576){
    int f = i / TT, t = i % TT;
    float acc = 0.f;
    #pragma unroll 8
    for (int nt = 0; nt < 32; ++nt) acc += pw1g[((size_t)(b*32 + nt))*CC*TT + i];
    w1s[i] = acc + S2*dt[b*CT + t*CC + f];
  }
  for (int i = tid; i < 1536; i += 576) ((float*)rh)[i] = rhs[(size_t)b*NN*TT + n0*TT + i];
  __syncthreads();
  for (int idx = tid; idx < 1536; idx += 576){
    int t = idx >> 6, n = idx & 63;
    float acc = 0.f;
    #pragma unroll 8
    for (int f = 0; f < CC; ++f) acc += u2s[f][n]*w1s[f*TT + t];
    lh[t][n] = acc;
  }
  __syncthreads();
  int t = tid / TT, s = tid % TT;
  float acc = 0.f;
  #pragma unroll 4
  for (int n = 0; n < 64; ++n) acc += lh[t][n]*rh[n][s];
  pprod[((size_t)(b*8 + ns))*576 + tid] = acc;
}

// ---------------- attention tail (att2): sum partials -> sigmoid -> ve -> softmax
__global__ void k_att_post2(const float* __restrict__ pprod, const float* __restrict__ ve,
                            const float* __restrict__ be, float* __restrict__ E){
  __shared__ float sig_s[TT*TT], E_s[TT*TT];
  int b = blockIdx.x, tid = threadIdx.x;
  float acc = 0.f;
  #pragma unroll
  for (int p = 0; p < 8; ++p) acc += pprod[((size_t)(b*8 + p))*576 + tid];
  sig_s[tid] = 1.f/(1.f + expf(-(acc + be[tid])));
  __syncthreads();
  {
    int t = tid / TT, r = tid % TT;
    float a = 0.f;
    for (int s = 0; s < TT; ++s) a += ve[t*TT + s]*sig_s[s*TT + r];
    E_s[tid] = a;
  }
  __syncthreads();
  if (tid < TT){
    int r = tid;
    float mx = -1e30f;
    for (int t = 0; t < TT; ++t) mx = fmaxf(mx, E_s[t*TT + r]);
    float sum = 0.f;
    for (int t = 0; t < TT; ++t) sum += expf(E_s[t*TT + r] - mx);
    float inv = 1.f/sum;
    for (int t = 0; t < TT; ++t) E[(size_t)b*TT*TT + t*TT + r] = expf(E_s[t*TT + r] - mx)*inv;
  }
}

// ---------------- att1 tail fused into xtat: E in LDS, never global
__global__ __launch_bounds__(256) void k_xtat(const float* __restrict__ ppr, const float* __restrict__ ve,
                       const float* __restrict__ be, const float* __restrict__ x,
                       const float* __restrict__ sw1, const float* __restrict__ sw2,
                       const float* __restrict__ sw3,
                       float* __restrict__ lx, float* __restrict__ r2){
  __shared__ float sig_s[576], E_s[576], sw1_s[TT], sw2_s[TT];
  int b = blockIdx.x >> 1, half = blockIdx.x & 1, tid = threadIdx.x;
  for (int i = tid; i < 576; i += 256){
    float acc = 0.f;
    #pragma unroll
    for (int p = 0; p < 8; ++p) acc += ppr[((size_t)(b*8 + p))*576 + i];
    sig_s[i] = 1.f/(1.f + expf(-(acc + be[i])));
  }
  if (tid < TT){ sw1_s[tid] = sw1[tid]; sw2_s[tid] = sw2[tid]; }
  __syncthreads();
  for (int i = tid; i < 576; i += 256){
    int t = i / TT, r = i % TT;
    float a = 0.f;
    for (int s = 0; s < TT; ++s) a += ve[t*TT + s]*sig_s[s*TT + r];
    E_s[i] = a;
  }
  __syncthreads();
  if (tid < TT){
    int r = tid;
    float mx = -1e30f;
    for (int t = 0; t < TT; ++t) mx = fmaxf(mx, E_s[t*TT + r]);
    float sum = 0.f;
    for (int t = 0; t < TT; ++t) sum += expf(E_s[t*TT + r] - mx);
    float inv = 1.f/sum;
    for (int t = 0; t < TT; ++t) E_s[t*TT + r] = expf(E_s[t*TT + r] - mx)*inv;
  }
  __syncthreads();
  int n = half*256 + tid;
  float xr[TT];
  const float* xp = x + (size_t)(b*NN + n)*TT;
  for (int t = 0; t < TT; ++t) xr[t] = xp[t];
  float l = 0.f, r = 0.f;
  for (int s = 0; s < TT; ++s){
    float acc = 0.f;
    for (int t = 0; t < TT; ++t) acc += xr[t]*E_s[t*TT + s];
    l += acc*sw1_s[s];
    r += acc*sw2_s[s];
  }
  lx[b*NN + n] = l;
  r2[b*NN + n] = r*sw3[0];
}

// ---------------- Qb[b][k][m] = bf16(sigmoid(lx[m]*r2[k] + sbT[k][m]))
__global__ __launch_bounds__(256) void k_sig(const float* __restrict__ lx, const float* __restrict__ r2,
                     const float* __restrict__ sbT, short* __restrict__ Qb){
  int b = blockIdx.y;
  int k = blockIdx.x*4 + (threadIdx.x >> 6);
  int m8 = (threadIdx.x & 63)*8;
  float r2k = r2[b*NN + k];
  const float* lxb = lx + b*NN;
  float4 l0 = *(const float4*)(lxb + m8);
  float4 l1 = *(const float4*)(lxb + m8 + 4);
  const float* sb = sbT + (size_t)k*NN + m8;
  float4 s0 = *(const float4*)(sb);
  float4 s1 = *(const float4*)(sb + 4);
  bf16x8 o;
  o[0] = f2bf(1.f/(1.f + __expf(-(l0.x*r2k + s0.x))));
  o[1] = f2bf(1.f/(1.f + __expf(-(l0.y*r2k + s0.y))));
  o[2] = f2bf(1.f/(1.f + __expf(-(l0.z*r2k + s0.z))));
  o[3] = f2bf(1.f/(1.f + __expf(-(l0.w*r2k + s0.w))));
  o[4] = f2bf(1.f/(1.f + __expf(-(l1.x*r2k + s1.x))));
  o[5] = f2bf(1.f/(1.f + __expf(-(l1.y*r2k + s1.y))));
  o[6] = f2bf(1.f/(1.f + __expf(-(l1.z*r2k + s1.z))));
  o[7] = f2bf(1.f/(1.f + __expf(-(l1.w*r2k + s1.w))));
  *(bf16x8*)(Qb + ((size_t)b*NN + k)*NN + m8) = o;
}

// ---------------- ST[b][k][n] = sum_m svB[n][m] * Qb[b][k][m]  (MFMA, BK=64 + XOR swizzle)
__global__ __launch_bounds__(256) void k_S0(const __hip_bfloat16* __restrict__ svB,
                    const short* __restrict__ Qb, float* __restrict__ ST){
  __shared__ __align__(16) short lA[128*64];
  __shared__ __align__(16) short lB[128*64];
  int kt = blockIdx.x, nt = blockIdx.y, b = blockIdx.z;
  int n0 = nt*128, k0 = kt*128;
  int tid = threadIdx.x;
  int w = tid >> 6, l = tid & 63;
  int wr = w >> 1, wc = w & 1;
  int lrow = l & 15, lk = l >> 4;
  int srow = l >> 3;
  int scol = ((l & 7) ^ srow)*8;
  int swz = (lrow & 7) << 3;
  f32x4 acc[4][4];
  #pragma unroll
  for (int m = 0; m < 4; ++m)
    #pragma unroll
    for (int n = 0; n < 4; ++n) acc[m][n] = (f32x4){0.f,0.f,0.f,0.f};
  for (int mk = 0; mk < NN; mk += 64){
    #pragma unroll
    for (int p = 0; p < 4; ++p){
      int c = p*4 + w;
      __builtin_amdgcn_global_load_lds(
        (const __attribute__((address_space(1))) void*)(svB + (size_t)(n0 + c*8 + srow)*NN + mk + scol),
        (__attribute__((address_space(3))) void*)(lA + c*512), 16, 0, 0);
      __builtin_amdgcn_global_load_lds(
        (const __attribute__((address_space(1))) void*)(Qb + ((size_t)b*NN + k0 + c*8 + srow)*NN + mk + scol),
        (__attribute__((address_space(3))) void*)(lB + c*512), 16, 0, 0);
    }
    __syncthreads();
    #pragma unroll
    for (int h = 0; h < 2; ++h){
      bf16x8 a[4], bv[4];
      #pragma unroll
      for (int m = 0; m < 4; ++m){
        int row = wr*64 + m*16 + lrow;
        a[m] = *(const bf16x8*)(lA + row*64 + ((h*32 + lk*8) ^ swz));
      }
      #pragma unroll
      for (int n = 0; n < 4; ++n){
        int row = wc*64 + n*16 + lrow;
        bv[n] = *(const bf16x8*)(lB + row*64 + ((h*32 + lk*8) ^ swz));
      }
      #pragma unroll
      for (int m = 0; m < 4; ++m)
        #pragma unroll
        for (int n = 0; n < 4; ++n)
          acc[m][n] = __builtin_amdgcn_mfma_f32_16x16x32_bf16(a[m], bv[n], acc[m][n], 0, 0, 0);
    }
    __syncthreads();
  }
  #pragma unroll
  for (int m = 0; m < 4; ++m){
    #pragma unroll
    for (int n = 0; n < 4; ++n){
      int col = k0 + wc*64 + n*16 + lrow;
      int row = n0 + wr*64 + m*16 + lk*4;
      float4 v; v.x = acc[m][n][0]; v.y = acc[m][n][1]; v.z = acc[m][n][2]; v.w = acc[m][n][3];
      *(float4*)(ST + (size_t)b*NN*NN + (size_t)col*NN + row) = v;
    }
  }
}

// ---------------- row softmax of ST -> P bf16 (unnormalized exp) + invZ
__global__ __launch_bounds__(256) void k_expS(const float* __restrict__ ST, short* __restrict__ P,
                      float* __restrict__ invZ){
  int b = blockIdx.y;
  int row = blockIdx.x*4 + (threadIdx.x >> 6);
  int l = threadIdx.x & 63;
  const float* R = ST + (size_t)b*NN*NN + (size_t)row*NN;
  float4 v0 = *(const float4*)(R + l*8);
  float4 v1 = *(const float4*)(R + l*8 + 4);
  float mx = fmaxf(fmaxf(fmaxf(v0.x,v0.y),fmaxf(v0.z,v0.w)),
                   fmaxf(fmaxf(v1.x,v1.y),fmaxf(v1.z,v1.w)));
  for (int off = 32; off; off >>= 1) mx = fmaxf(mx, __shfl_xor(mx, off));
  v0.x = __expf(v0.x-mx); v0.y = __expf(v0.y-mx); v0.z = __expf(v0.z-mx); v0.w = __expf(v0.w-mx);
  v1.x = __expf(v1.x-mx); v1.y = __expf(v1.y-mx); v1.z = __expf(v1.z-mx); v1.w = __expf(v1.w-mx);
  float s = v0.x+v0.y+v0.z+v0.w+v1.x+v1.y+v1.z+v1.w;
  for (int off = 32; off; off >>= 1) s += __shfl_xor(s, off);
  bf16x8 o;
  o[0]=f2bf(v0.x); o[1]=f2bf(v0.y); o[2]=f2bf(v0.z); o[3]=f2bf(v0.w);
  o[4]=f2bf(v1.x); o[5]=f2bf(v1.y); o[6]=f2bf(v1.z); o[7]=f2bf(v1.w);
  *(bf16x8*)(P + ((size_t)b*NN + row)*NN + l*8) = o;
  if (l == 0) invZ[b*NN + row] = 1.f/s;
}

// ---------------- tmp_kc[b] = (P[b] .* chebT[kc]) @ xT[b]^T (MFMA, BK=64 + XOR swizzle)
__global__ __launch_bounds__(256) void k_tmpG(const short* __restrict__ P, const short* __restrict__ chebT,
                      const short* __restrict__ xT, const float* __restrict__ invZ,
                      float* __restrict__ tmp){
  __shared__ __align__(16) short lP[128*64];
  __shared__ __align__(16) short lC[128*64];
  __shared__ __align__(16) short lX[32*64];
  __shared__ float iz_s[128];
  int it = blockIdx.x, kc = blockIdx.y, b = blockIdx.z;
  int i0 = it*128;
  int tid = threadIdx.x;
  int w = tid >> 6, l = tid & 63;
  int lrow = l & 15, lk = l >> 4;
  int srow = l >> 3;
  int scol = ((l & 7) ^ srow)*8;
  int swz = (lrow & 7) << 3;
  if (tid < 128) iz_s[tid] = invZ[b*NN + i0 + tid];
  f32x4 acc[2][2];
  #pragma unroll
  for (int m = 0; m < 2; ++m)
    #pragma unroll
    for (int n = 0; n < 2; ++n) acc[m][n] = (f32x4){0.f,0.f,0.f,0.f};
  for (int j0 = 0; j0 < NN; j0 += 64){
    #pragma unroll
    for (int p = 0; p < 4; ++p){
      int c = p*4 + w;
      __builtin_amdgcn_global_load_lds(
        (const __attribute__((address_space(1))) void*)(P + ((size_t)b*NN + i0 + c*8 + srow)*NN + j0 + scol),
        (__attribute__((address_space(3))) void*)(lP + c*512), 16, 0, 0);
      __builtin_amdgcn_global_load_lds(
        (const __attribute__((address_space(1))) void*)(chebT + ((size_t)kc*NN + i0 + c*8 + srow)*NN + j0 + scol),
        (__attribute__((address_space(3))) void*)(lC + c*512), 16, 0, 0);
    }
    {
      int c = w;
      __builtin_amdgcn_global_load_lds(
        (const __attribute__((address_space(1))) void*)(xT + ((size_t)b*32 + c*8 + srow)*NN + j0 + scol),
        (__attribute__((address_space(3))) void*)(lX + c*512), 16, 0, 0);
    }
    __syncthreads();
    #pragma unroll
    for (int h = 0; h < 2; ++h){
      bf16x8 bv[2];
      #pragma unroll
      for (int n = 0; n < 2; ++n)
        bv[n] = *(const bf16x8*)(lX + (n*16 + lrow)*64 + ((h*32 + lk*8) ^ swz));
      #pragma unroll
      for (int m = 0; m < 2; ++m){
        int r = w*32 + m*16 + lrow;
        bf16x8 pp = *(const bf16x8*)(lP + r*64 + ((h*32 + lk*8) ^ swz));
        bf16x8 cc = *(const bf16x8*)(lC + r*64 + ((h*32 + lk*8) ^ swz));
        bf16x8 af;
        #pragma unroll
        for (int e = 0; e < 8; ++e) af[e] = f2bf(bf2f(pp[e])*bf2f(cc[e]));
        #pragma unroll
        for (int n = 0; n < 2; ++n)
          acc[m][n] = __builtin_amdgcn_mfma_f32_16x16x32_bf16(af, bv[n], acc[m][n], 0, 0, 0);
      }
    }
    __syncthreads();
  }
  #pragma unroll
  for (int m = 0; m < 2; ++m){
    #pragma unroll
    for (int n = 0; n < 2; ++n){
      int t = n*16 + lrow;
      if (t < TT){
        #pragma unroll
        for (int j = 0; j < 4; ++j){
          int ir = w*32 + m*16 + lk*4 + j;
          tmp[((size_t)(kc*BB + b)*NN + i0 + ir)*TT + t] = acc[m][n][j]*iz_s[ir];
        }
      }
    }
  }
}

// ---------------- att2: per-16-n-tile two-pass: rhsg + partial w1g
__global__ __launch_bounds__(384) void k_gsum(const float* __restrict__ tmp, const float* __restrict__ theta,
                      const float* __restrict__ u1b, const float* __restrict__ u3b,
                      const float* __restrict__ du3b,
                      float* __restrict__ rhsg, float* __restrict__ pw1g){
  __shared__ float A0[16*TT], A1[16*TT], A2[16*TT], th_s[192], u3_s[CC], u1_s[16], du_s[TT];
  int nt = blockIdx.x, b = blockIdx.y;
  int n0 = nt*16, tid = threadIdx.x;
  for (int i = tid; i < 192; i += 384) th_s[i] = theta[i];
  if (tid < CC) u3_s[tid] = u3b[tid];
  if (tid < 16) u1_s[tid] = u1b[n0 + tid];
  if (tid < TT) du_s[tid] = du3b[b*TT + tid];
  A0[tid] = tmp[((size_t)(0*BB + b)*NN + n0)*TT + tid];
  A1[tid] = tmp[((size_t)(1*BB + b)*NN + n0)*TT + tid];
  A2[tid] = tmp[((size_t)(2*BB + b)*NN + n0)*TT + tid];
  __syncthreads();
  {
    int nn = tid / TT, t = tid % TT;
    float a0 = A0[nn*TT + t], a1 = A1[nn*TT + t], a2 = A2[nn*TT + t];
    float acc = du_s[t];
    #pragma unroll 8
    for (int f = 0; f < CC; ++f){
      float v = th_s[f]*a0 + th_s[64 + f]*a1 + th_s[128 + f]*a2;
      acc += u3_s[f]*fmaxf(v, 0.f);
    }
    rhsg[(size_t)b*NN*TT + (n0 + nn)*TT + t] = acc;
  }
  #pragma unroll
  for (int p = 0; p < 4; ++p){
    int o = tid + p*384;
    int f = o / TT, t = o % TT;
    float t0 = th_s[f], t1 = th_s[64 + f], t2 = th_s[128 + f];
    float acc = 0.f;
    #pragma unroll
    for (int m = 0; m < 16; ++m){
      float v = t0*A0[m*TT + t] + t1*A1[m*TT + t] + t2*A2[m*TT + t];
      acc += u1_s[m]*fmaxf(v, 0.f);
    }
    pw1g[((size_t)(b*32 + nt))*CC*TT + o] = acc;
  }
}

// ---------------- g2 (bf16) = relu(theta·tmp) @ E2 — register-accumulated, broadcast E reads
__global__ __launch_bounds__(256) void k_g2(const float* __restrict__ tmp, const float* __restrict__ E2,
                     const float* __restrict__ theta, __hip_bfloat16* __restrict__ g2){
  __shared__ float E_s[TT*TT], th_s[192], tr[3*4*TT];
  __shared__ float g_s[256*25];   // [nn*64+f][s], pad 24->25
  int b = blockIdx.y, n0 = blockIdx.x*4, tid = threadIdx.x;
  for (int i = tid; i < 576; i += 256) E_s[i] = E2[(size_t)b*576 + i];
  for (int i = tid; i < 192; i += 256) th_s[i] = theta[i];
  for (int i = tid; i < 288; i += 256){
    int k = i / 96, rem = i % 96, nn = rem / TT, s = rem % TT;
    tr[i] = tmp[((size_t)(k*BB + b)*NN + n0 + nn)*TT + s];
  }
  __syncthreads();
  for (int idx = tid; idx < 4*CC*TT; idx += 256){
    int nn = idx / (CC*TT), rem = idx % (CC*TT), f = rem / TT, s = rem % TT;
    float v = th_s[f]*tr[nn*TT + s] + th_s[64 + f]*tr[96 + nn*TT + s] + th_s[128 + f]*tr[192 + nn*TT + s];
    g_s[(nn*64 + f)*25 + s] = fmaxf(v, 0.f);
  }
  __syncthreads();
  const float* gr = g_s + tid*25;
  float acc[TT];
  #pragma unroll
  for (int t = 0; t < TT; ++t) acc[t] = 0.f;
  #pragma unroll
  for (int s = 0; s < TT; ++s){
    float gs = gr[s];
    const float* er = E_s + s*TT;
    #pragma unroll
    for (int t = 0; t < TT; ++t) acc[t] += gs*er[t];
  }
  int nn = tid >> 6, f = tid & 63;
  __hip_bfloat16* go = g2 + (size_t)(b*NN + n0 + nn)*CT + f*TT;
  #pragma unroll
  for (int q = 0; q < 3; ++q){
    bf16x8 o;
    #pragma unroll
    for (int e = 0; e < 8; ++e) o[e] = f2bf(acc[q*8 + e]);
    *(bf16x8*)((short*)go + q*8) = o;
  }
}

// ---------------- tlin(bf16) = A @ W^T + l1_b — BK=64, XOR-swizzled LDS, XCD-swizzled grid
__global__ __launch_bounds__(256) void k_gemm_bf16(const __hip_bfloat16* __restrict__ A,
                      const __hip_bfloat16* __restrict__ W,
                      const float* __restrict__ bias, __hip_bfloat16* __restrict__ Cout){
  int bid = blockIdx.x;
  int nb = (bid & 7)*192 + (bid >> 3);
  int o0 = (nb % 12)*128, i0 = (nb / 12)*128;
  __shared__ __align__(16) short lA[128*64];
  __shared__ __align__(16) short lB[128*64];
  int tid = threadIdx.x;
  int w = tid >> 6, l = tid & 63;
  int wr = w >> 1, wc = w & 1;
  int lrow = l & 15, lk = l >> 4;
  int srow = l >> 3;
  int scol = ((l & 7) ^ srow)*8;
  int swz = (lrow & 7) << 3;
  f32x4 acc[4][4];
  #pragma unroll
  for (int m = 0; m < 4; ++m)
    #pragma unroll
    for (int n = 0; n < 4; ++n) acc[m][n] = (f32x4){0.f,0.f,0.f,0.f};
  for (int k0 = 0; k0 < CT; k0 += 64){
    #pragma unroll
    for (int p = 0; p < 4; ++p){
      int c = p*4 + w;
      __builtin_amdgcn_global_load_lds(
        (const __attribute__((address_space(1))) void*)(A + (size_t)(i0 + c*8 + srow)*CT + k0 + scol),
        (__attribute__((address_space(3))) void*)(lA + c*512), 16, 0, 0);
      __builtin_amdgcn_global_load_lds(
        (const __attribute__((address_space(1))) void*)(W + (size_t)(o0 + c*8 + srow)*CT + k0 + scol),
        (__attribute__((address_space(3))) void*)(lB + c*512), 16, 0, 0);
    }
    __syncthreads();
    #pragma unroll
    for (int h = 0; h < 2; ++h){
      bf16x8 a[4], bv[4];
      #pragma unroll
      for (int m = 0; m < 4; ++m){
        int row = wr*64 + m*16 + lrow;
        a[m] = *(const bf16x8*)(lA + row*64 + ((h*32 + lk*8) ^ swz));
      }
      #pragma unroll
      for (int n = 0; n < 4; ++n){
        int row = wc*64 + n*16 + lrow;
        bv[n] = *(const bf16x8*)(lB + row*64 + ((h*32 + lk*8) ^ swz));
      }
      #pragma unroll
      for (int m = 0; m < 4; ++m)
        #pragma unroll
        for (int n = 0; n < 4; ++n)
          acc[m][n] = __builtin_amdgcn_mfma_f32_16x16x32_bf16(a[m], bv[n], acc[m][n], 0, 0, 0);
    }
    __syncthreads();
  }
  #pragma unroll
  for (int m = 0; m < 4; ++m){
    #pragma unroll
    for (int n = 0; n < 4; ++n){
      int o = o0 + wc*64 + n*16 + lrow;
      float bo = bias[o];
      #pragma unroll
      for (int j = 0; j < 4; ++j){
        int i = i0 + wr*64 + m*16 + lk*4 + j;
        Cout[(size_t)i*CT + o] = __float2bfloat16(acc[m][n][j] + bo);
      }
    }
  }
}

// ---------------- reshape + residual + relu + LayerNorm (LDS-staged, bf16 tlin)
__global__ __launch_bounds__(128) void k_final(const __hip_bfloat16* __restrict__ tlin, const float* __restrict__ x,
                      const float* __restrict__ res_w, const float* __restrict__ res_b,
                      const float* __restrict__ ln_g, const float* __restrict__ ln_b,
                      float* __restrict__ out){
  __shared__ float Ls[64][132];
  __shared__ float rw_s[64], rb_s[64], lg_s[64], lb_s[64];
  int ot = blockIdx.x, dlt = blockIdx.y, b = blockIdx.z;
  int o0 = ot*128, tid = threadIdx.x;
  if (tid < 64){ rw_s[tid]=res_w[tid]; rb_s[tid]=res_b[tid]; lg_s[tid]=ln_g[tid]; lb_s[tid]=ln_b[tid]; }
  const __hip_bfloat16* tb = tlin + (size_t)b*NN*CT;
  #pragma unroll 4
  for (int c = 0; c < 64; ++c)
    Ls[c][tid] = __bfloat162float(tb[(size_t)(c*8 + dlt)*CT + o0 + tid]);
  __syncthreads();
  int p = dlt*CT + o0 + tid;
  int np = p / TT, tp = p % TT;
  float xv = x[(size_t)(b*NN + np)*TT + tp];
  float z[CC];
  float sum = 0.f, sq = 0.f;
  #pragma unroll
  for (int c = 0; c < CC; ++c){
    float v = Ls[c][tid] + xv*rw_s[c] + rb_s[c];
    v = fmaxf(v, 0.f);
    z[c] = v; sum += v; sq += v*v;
  }
  float mu = sum*(1.f/64.f);
  float var = sq*(1.f/64.f) - mu*mu;
  float rstd = rsqrtf(var + 1e-5f);
  float* ob = out + (size_t)(b*NN + np)*CC*TT + tp;
  #pragma unroll
  for (int c = 0; c < CC; ++c)
    ob[c*TT] = (z[c] - mu)*rstd*lg_s[c] + lb_s[c];
}

extern "C" void kernel_launch(void* const* d_in, const int* in_sizes, int n_in,
                              void* d_out, int out_size, void* d_ws, size_t ws_size,
                              hipStream_t stream){
  const float* x    = (const float*)d_in[0];
  const float* y    = (const float*)d_in[1];
  const float* tl_w = (const float*)d_in[2];
  const float* tl_b = (const float*)d_in[3];
  const float* u0_w = (const float*)d_in[4];
  const float* u0_b = (const float*)d_in[5];
  const float* u1a  = (const float*)d_in[6];
  const float* u2a  = (const float*)d_in[7];
  const float* u3a  = (const float*)d_in[8];
  const float* be_a = (const float*)d_in[9];
  const float* ve_a = (const float*)d_in[10];
  const float* u1b  = (const float*)d_in[11];
  const float* u2b  = (const float*)d_in[12];
  const float* u3b  = (const float*)d_in[13];
  const float* be_b = (const float*)d_in[14];
  const float* ve_b = (const float*)d_in[15];
  const float* sw1  = (const float*)d_in[16];
  const float* sw2  = (const float*)d_in[17];
  const float* sw3  = (const float*)d_in[18];
  const float* s_bs = (const float*)d_in[19];
  const float* s_vs = (const float*)d_in[20];
  const float* cheb = (const float*)d_in[21];
  const float* theta= (const float*)d_in[22];
  const float* l1_w = (const float*)d_in[23];
  const float* l1_b = (const float*)d_in[24];
  const float* res_w= (const float*)d_in[25];
  const float* res_b= (const float*)d_in[26];
  const float* ln_g = (const float*)d_in[27];
  const float* ln_b = (const float*)d_in[28];
  float* out = (float*)d_out;
  float* ws  = (float*)d_ws;

  // ws layout (floats). big regions & lifetimes (verified, as R17):
  //  [0, 3.79M): WB/yB/pdt (k_pre -> k_small)        [0, 8.39M): ST (k_S0 -> k_expS)
  //  [8.39M, 12.58M): Pb (k_expS -> k_tmpG)          [12.58M, 13.25M): xTb/iZ/chT (k_pre -> k_tmpG)
  //  [13.25M, 14.43M): Wb bf16 (k_pre -> k_gemm)     [14.43M, 18.63M): Qb (k_sig -> k_S0)
  //  [18.63M, 18.89M): sbT (k_pre -> k_sig)
  //  pw1g [0, 1.57M) (k_gsum -> k_prodB, after ST dead); tlin bf16 [0, 12.58M) (k_gemm -> k_final).
  float* dt   = ws;               // 49152
  float* E    = dt   + 49152;     // 18432 (E2)
  float* lxp  = E    + 18432;     // 16384
  float* r2p  = lxp  + 16384;     // 16384
  float* w0u3 = r2p  + 16384;     // 640
  float* b0u3 = w0u3 + 640;       // 64
  float* sums = b0u3 + 64;        // 64
  float* du3a = sums + 64;        // 768
  float* du3b = du3a + 768;       // 768
  float* w1a  = du3b + 768;       // 49152
  float* w1g  = w1a  + 49152;     // 49152 (unused)
  float* lhs1 = w1g  + 49152;     // 393216 (unused)
  float* rhs1 = lhs1 + 393216;    // 393216 (unused)
  float* lhsg = rhs1 + 393216;    // 393216 (unused)
  float* rhsg = lhsg + 393216;    // 393216
  float* svBf = rhsg + 393216;    // 131072 (bf16 512x512)
  float* ppr  = svBf + 131072;    // 147456
  float* tmp  = ppr  + 147456;    // 1179648
  float* big  = tmp  + 1179648;   // 25165824 floats
  float* ST   = big;
  float* pw1g = big;
  __hip_bfloat16* tlin = (__hip_bfloat16*)big;
  __hip_bfloat16* WB = (__hip_bfloat16*)big;
  __hip_bfloat16* yB = (__hip_bfloat16*)(big + 2801664);
  float* pdt = big + 2801664 + 58368;
  short* Pb  = (short*)(big + 8388608);
  short* xTb = (short*)(big + 12582912);
  float* iZ  = big + 12582912 + 262144;
  short* chT = (short*)(big + 12582912 + 262144 + 16384);
  __hip_bfloat16* Wb = (__hip_bfloat16*)(big + 13254656);    // 1536x1536 bf16
  short* Qb  = (short*)(big + 14434304);                     // 32x512x512 bf16
  float* sbT = big + 18628608;                               // 512x512 fp32
  __hip_bfloat16* svB = (__hip_bfloat16*)svBf;
  __hip_bfloat16* g2b = (__hip_bfloat16*)d_out;
  (void)w1g; (void)lhs1; (void)rhs1; (void)lhsg;

  k_pre<<<dim3(6410), dim3(256), 0, stream>>>(s_vs, y, tl_w, cheb, x, l1_w, s_bs,
                                              u0_w, u0_b, u1a, u3a, u1b,
                                              svB, yB, WB, chT, xTb, Wb, sbT,
                                              w0u3, b0u3, sums);
  k_dtgemm<<<dim3(6, 19), dim3(256), 0, stream>>>(yB, WB, pdt);
  k_small<<<dim3(32), dim3(256), 0, stream>>>(x, pdt, tl_b, u0_w, u0_b, u1a, u3a, u3b, sums, dt, w1a, du3a, du3b);
  k_prodA<<<dim3(8, 32), dim3(576), 0, stream>>>(x, w0u3, b0u3, du3a, u2a, w1a, ppr);
  k_xtat<<<dim3(64), dim3(256), 0, stream>>>(ppr, ve_a, be_a, x, sw1, sw2, sw3, lxp, r2p);
  k_sig<<<dim3(128, 32), dim3(256), 0, stream>>>(lxp, r2p, sbT, Qb);
  k_S0<<<dim3(4, 4, 32), dim3(256), 0, stream>>>(svB, Qb, ST);
  k_expS<<<dim3(128, 32), dim3(256), 0, stream>>>(ST, Pb, iZ);
  k_tmpG<<<dim3(4, 3, 32), dim3(256), 0, stream>>>(Pb, chT, xTb, iZ, tmp);
  k_gsum<<<dim3(32, 32), dim3(384), 0, stream>>>(tmp, theta, u1b, u3b, du3b, rhsg, pw1g);
  k_prodB<<<dim3(8, 32), dim3(576), 0, stream>>>(u2b, pw1g, dt, sums, rhsg, ppr);
  k_att_post2<<<dim3(32), dim3(576), 0, stream>>>(ppr, ve_b, be_b, E);
  k_g2<<<dim3(128, 32), dim3(256), 0, stream>>>(tmp, E, theta, g2b);
  k_gemm_bf16<<<dim3(1536), dim3(256), 0, stream>>>(g2b, Wb, l1_b, tlin);
  k_final<<<dim3(12, 8, 32), dim3(128), 0, stream>>>(tlin, x, res_w, res_b, ln_g, ln_b, out);
}

// Round 19
// 334.206 us; speedup vs baseline: 1.0197x; 1.0197x over previous
//
#include <hip/hip_runtime.h>
#include <hip/hip_bf16.h>
#include <math.h>

#define BB 32
#define NN 512
#define TT 24
#define CC 64
#define CT 1536   // CC*TT
#define YD 3624   // 151*TT
#define YP 3648   // YD padded to 114*32

typedef __attribute__((ext_vector_type(4))) float f32x4;
typedef __attribute__((ext_vector_type(8))) short bf16x8;

static __device__ __forceinline__ short f2bf(float f){
  union { float f; unsigned u; } v; v.f = f;
  unsigned r = (v.u + 0x7FFF + ((v.u >> 16) & 1)) >> 16;
  return (short)r;
}
static __device__ __forceinline__ float bf2f(short s){
  union { unsigned u; float f; } v; v.u = ((unsigned)(unsigned short)s) << 16;
  return v.f;
}

// ---------------- fused preprocessing:
// [0,256) convS | [256,313) pad(y) | [313,3049) pad(tl_w) | [3049,3817) chebT
// [3817,3849) xT | [3849,6153) convW(l1_w) | [6153,6409) sbT | 6409: prep0
__global__ __launch_bounds__(256) void k_pre(const float* __restrict__ s_vs, const float* __restrict__ y,
                    const float* __restrict__ tl_w, const float* __restrict__ cheb,
                    const float* __restrict__ x, const float* __restrict__ l1_w,
                    const float* __restrict__ s_bs,
                    const float* __restrict__ u0_w, const float* __restrict__ u0_b,
                    const float* __restrict__ u1a, const float* __restrict__ u3a,
                    const float* __restrict__ u1b,
                    __hip_bfloat16* __restrict__ svB, __hip_bfloat16* __restrict__ yB,
                    __hip_bfloat16* __restrict__ WB, short* __restrict__ chT,
                    short* __restrict__ xTb, __hip_bfloat16* __restrict__ Wb,
                    float* __restrict__ sbT,
                    float* __restrict__ w0u3, float* __restrict__ b0u3, float* __restrict__ sums){
  __shared__ float shm[512*25];
  int bb = blockIdx.x, tid = threadIdx.x;
  if (bb < 256){
    int i = (bb*256 + tid)*4;
    float4 v = *(const float4*)(s_vs + i);
    svB[i+0] = __float2bfloat16(v.x);
    svB[i+1] = __float2bfloat16(v.y);
    svB[i+2] = __float2bfloat16(v.z);
    svB[i+3] = __float2bfloat16(v.w);
  } else if (bb < 313){
    int gid = (bb - 256)*256 + tid;
    int r = gid / (YP/8), c8 = (gid % (YP/8))*8;
    if (r < 32){
      bf16x8 o;
      if (c8 < YD){
        float4 a = *(const float4*)(y + (size_t)r*YD + c8);
        float4 b = *(const float4*)(y + (size_t)r*YD + c8 + 4);
        o[0]=f2bf(a.x); o[1]=f2bf(a.y); o[2]=f2bf(a.z); o[3]=f2bf(a.w);
        o[4]=f2bf(b.x); o[5]=f2bf(b.y); o[6]=f2bf(b.z); o[7]=f2bf(b.w);
      } else {
        for (int j = 0; j < 8; ++j) o[j] = 0;
      }
      *(bf16x8*)((short*)yB + (size_t)r*YP + c8) = o;
    }
  } else if (bb < 3049){
    int gid = (bb - 313)*256 + tid;
    int r = gid / (YP/8), c8 = (gid % (YP/8))*8;
    if (r < 1536){
      bf16x8 o;
      if (c8 < YD){
        float4 a = *(const float4*)(tl_w + (size_t)r*YD + c8);
        float4 b = *(const float4*)(tl_w + (size_t)r*YD + c8 + 4);
        o[0]=f2bf(a.x); o[1]=f2bf(a.y); o[2]=f2bf(a.z); o[3]=f2bf(a.w);
        o[4]=f2bf(b.x); o[5]=f2bf(b.y); o[6]=f2bf(b.z); o[7]=f2bf(b.w);
      } else {
        for (int j = 0; j < 8; ++j) o[j] = 0;
      }
      *(bf16x8*)((short*)WB + (size_t)r*YP + c8) = o;
    }
  } else if (bb < 3817){
    int q = bb - 3049;
    int jt = q & 15, it = (q >> 4) & 15, k = q >> 8;
    float (*ts)[33] = (float(*)[33])shm;
    int c = tid & 31, r8 = tid >> 5;
    #pragma unroll
    for (int p = 0; p < 4; ++p){
      int r = p*8 + r8;
      ts[r][c] = cheb[((size_t)k*NN + jt*32 + r)*NN + it*32 + c];
    }
    __syncthreads();
    #pragma unroll
    for (int p = 0; p < 4; ++p){
      int r = p*8 + r8;
      chT[((size_t)k*NN + it*32 + r)*NN + jt*32 + c] = f2bf(ts[c][r]);
    }
  } else if (bb < 3849){
    int b = bb - 3817;
    for (int idx = tid; idx < NN*TT; idx += 256){
      int j = idx / TT, t = idx % TT;
      shm[j*25 + t] = x[(size_t)b*NN*TT + idx];
    }
    __syncthreads();
    for (int u = tid; u < 32*64; u += 256){
      int t = u >> 6, j8 = (u & 63)*8;
      bf16x8 o;
      if (t < TT){
        #pragma unroll
        for (int e = 0; e < 8; ++e) o[e] = f2bf(shm[(j8 + e)*25 + t]);
      } else {
        #pragma unroll
        for (int e = 0; e < 8; ++e) o[e] = 0;
      }
      *(bf16x8*)(xTb + ((size_t)b*32 + t)*NN + j8) = o;
    }
  } else if (bb < 6153){
    int i = ((bb - 3849)*256 + tid)*4;
    float4 v = *(const float4*)(l1_w + i);
    Wb[i+0] = __float2bfloat16(v.x);
    Wb[i+1] = __float2bfloat16(v.y);
    Wb[i+2] = __float2bfloat16(v.z);
    Wb[i+3] = __float2bfloat16(v.w);
  } else if (bb < 6409){
    int q = bb - 6153;
    int mt = q & 15, kt = q >> 4;
    float (*ts)[33] = (float(*)[33])shm;
    int c = tid & 31, r8 = tid >> 5;
    #pragma unroll
    for (int p = 0; p < 4; ++p){
      int r = p*8 + r8;
      ts[r][c] = s_bs[(size_t)(mt*32 + r)*NN + kt*32 + c];
    }
    __syncthreads();
    #pragma unroll
    for (int p = 0; p < 4; ++p){
      int r = p*8 + r8;
      sbT[(size_t)(kt*32 + r)*NN + mt*32 + c] = ts[c][r];
    }
  } else {
    for (int e = tid; e < 576; e += 256){
      int tp = e / TT, t = e % TT;
      float acc = 0.f;
      for (int f = 0; f < CC; ++f) acc += u3a[f]*u0_w[(f*TT + tp)*TT + t];
      w0u3[e] = acc;
    }
    if (tid >= 64 && tid < 64 + TT){
      int t = tid - 64;
      float acc = 0.f;
      for (int f = 0; f < CC; ++f) acc += u3a[f]*u0_b[f*TT + t];
      b0u3[t] = acc;
    }
    if (tid == 0){ float s = 0.f; for (int n = 0; n < NN; ++n) s += u1a[n]; sums[0] = s; }
    if (tid == 1){ float s = 0.f; for (int n = 0; n < NN; ++n) s += u1b[n]; sums[1] = s; }
  }
}

// ---------------- pdt[ks][32][1536] = y-slice @ tl_w-slice^T  (MFMA, M=32, BK=32)
__global__ __launch_bounds__(256) void k_dtgemm(const __hip_bfloat16* __restrict__ yB,
                       const __hip_bfloat16* __restrict__ WB, float* __restrict__ pdt){
  __shared__ __align__(16) short lA[32*32];
  __shared__ __align__(16) short lB[256*32];
  int nt = blockIdx.x, ks = blockIdx.y;
  int o0 = nt*256;
  int tid = threadIdx.x;
  int w = tid >> 6, l = tid & 63;
  int lrow = l & 15, lk = l >> 4;
  f32x4 acc[2][4];
  #pragma unroll
  for (int m = 0; m < 2; ++m)
    #pragma unroll
    for (int n = 0; n < 4; ++n) acc[m][n] = (f32x4){0.f,0.f,0.f,0.f};
  for (int step = 0; step < 6; ++step){
    int k0 = (ks*6 + step)*32;
    #pragma unroll
    for (int p = 0; p < 4; ++p){
      int c = p*4 + w;
      int off = c*512 + l*8;
      int row = off >> 5, col = off & 31;
      __builtin_amdgcn_global_load_lds(
        (const __attribute__((address_space(1))) void*)((const short*)WB + (size_t)(o0 + row)*YP + k0 + col),
        (__attribute__((address_space(3))) void*)(lB + c*512), 16, 0, 0);
    }
    if (w < 2){
      int off = w*512 + l*8;
      int row = off >> 5, col = off & 31;
      __builtin_amdgcn_global_load_lds(
        (const __attribute__((address_space(1))) void*)((const short*)yB + (size_t)row*YP + k0 + col),
        (__attribute__((address_space(3))) void*)(lA + w*512), 16, 0, 0);
    }
    __syncthreads();
    bf16x8 a[2], bv[4];
    #pragma unroll
    for (int m = 0; m < 2; ++m) a[m] = *(const bf16x8*)(lA + (m*16 + lrow)*32 + lk*8);
    #pragma unroll
    for (int n = 0; n < 4; ++n) bv[n] = *(const bf16x8*)(lB + (w*64 + n*16 + lrow)*32 + lk*8);
    #pragma unroll
    for (int m = 0; m < 2; ++m)
      #pragma unroll
      for (int n = 0; n < 4; ++n)
        acc[m][n] = __builtin_amdgcn_mfma_f32_16x16x32_bf16(a[m], bv[n], acc[m][n], 0, 0, 0);
    __syncthreads();
  }
  #pragma unroll
  for (int m = 0; m < 2; ++m){
    #pragma unroll
    for (int n = 0; n < 4; ++n){
      int o = o0 + w*64 + n*16 + lrow;
      #pragma unroll
      for (int j = 0; j < 4; ++j){
        int b = m*16 + lk*4 + j;
        pdt[((size_t)(ks*32 + b))*CT + o] = acc[m][n][j];
      }
    }
  }
}

// ---------------- per-b: dt reduce + xu, du3a, du3b, w1a
__global__ void k_small(const float* __restrict__ x, const float* __restrict__ pdt,
                        const float* __restrict__ tl_b,
                        const float* __restrict__ u0_w, const float* __restrict__ u0_b,
                        const float* __restrict__ u1a, const float* __restrict__ u3a,
                        const float* __restrict__ u3b, const float* __restrict__ sums,
                        float* __restrict__ dt,
                        float* __restrict__ w1a, float* __restrict__ du3a, float* __restrict__ du3b){
  __shared__ float xu_s[TT], u1a_s[NN], dt_s[CT];
  int b = blockIdx.x, tid = threadIdx.x;
  for (int o = tid; o < CT; o += 256){
    float acc = tl_b[o];
    #pragma unroll
    for (int ks = 0; ks < 19; ++ks) acc += pdt[((size_t)(ks*32 + b))*CT + o];
    dt_s[o] = acc;
    dt[b*CT + o] = acc;
  }
  for (int i = tid; i < NN; i += 256) u1a_s[i] = u1a[i];
  __syncthreads();
  int wv = tid >> 6, ln = tid & 63;
  for (int t = wv; t < TT; t += 4){
    float acc = 0.f;
    for (int n = ln; n < NN; n += 64) acc += u1a_s[n]*x[(size_t)(b*NN + n)*TT + t];
    for (int off = 32; off; off >>= 1) acc += __shfl_down(acc, off);
    if (ln == 0) xu_s[t] = acc;
  }
  if (tid < TT){
    float a = 0.f, c = 0.f;
    for (int f = 0; f < CC; ++f){
      float d = dt_s[tid*CC + f];
      a += u3a[f]*d; c += u3b[f]*d;
    }
    du3a[b*TT + tid] = a;
    du3b[b*TT + tid] = c;
  }
  __syncthreads();
  float S1 = sums[0];
  for (int idx = tid; idx < CC*TT; idx += 256){
    int f = idx / TT, tp = idx % TT;
    float acc = 0.f;
    const float* wrow = u0_w + (f*TT + tp)*TT;
    for (int t = 0; t < TT; ++t) acc += wrow[t]*xu_s[t];
    w1a[b*CC*TT + idx] = acc + S1*(u0_b[f*TT + tp] + dt_s[tp*CC + f]);
  }
}

// ---------------- att1 fused: rh inline from x/w0u3, lh from u2/w1, partial product
__global__ __launch_bounds__(576) void k_prodA(const float* __restrict__ x, const float* __restrict__ w0u3,
                      const float* __restrict__ b0u3, const float* __restrict__ du3a,
                      const float* __restrict__ u2, const float* __restrict__ w1,
                      float* __restrict__ pprod){
  __shared__ float u2s[64][65], w1s[CC*TT], lh[TT][64], rh[64][TT], xs[64*TT], w0_s[576], bd_s[TT];
  int ns = blockIdx.x, b = blockIdx.y;
  int n0 = ns*64, tid = threadIdx.x;
  for (int i = tid; i < 4096; i += 576){ int f = i >> 6, n = i & 63; u2s[f][n] = u2[f*NN + n0 + n]; }
  for (int i = tid; i < CC*TT; i += 576) w1s[i] = w1[b*CC*TT + i];
  for (int i = tid; i < 1536; i += 576) xs[i] = x[(size_t)(b*NN + n0)*TT + i];
  w0_s[tid] = w0u3[tid];
  if (tid < TT) bd_s[tid] = b0u3[tid] + du3a[b*TT + tid];
  __syncthreads();
  for (int idx = tid; idx < 1536; idx += 576){
    int n = idx / TT, tp = idx % TT;
    float acc = bd_s[tp];
    const float* wr = w0_s + tp*TT;
    const float* xr = xs + n*TT;
    #pragma unroll
    for (int t = 0; t < TT; ++t) acc += wr[t]*xr[t];
    rh[n][tp] = acc;
  }
  for (int idx = tid; idx < 1536; idx += 576){
    int t = idx >> 6, n = idx & 63;
    float acc = 0.f;
    #pragma unroll 8
    for (int f = 0; f < CC; ++f) acc += u2s[f][n]*w1s[f*TT + t];
    lh[t][n] = acc;
  }
  __syncthreads();
  int t = tid / TT, s = tid % TT;
  float acc = 0.f;
  #pragma unroll 4
  for (int n = 0; n < 64; ++n) acc += lh[t][n]*rh[n][s];
  pprod[((size_t)(b*8 + ns))*576 + tid] = acc;
}

// ---------------- att2: lhs+prod fused, w1 built inline from pw1g partials + S2*dt
__global__ __launch_bounds__(576) void k_prodB(const float* __restrict__ u2, const float* __restrict__ pw1g,
                      const float* __restrict__ dt, const float* __restrict__ sums,
                      const float* __restrict__ rhs, float* __restrict__ pprod){
  __shared__ float u2s[64][65], w1s[CC*TT], lh[TT][64], rh[64][TT];
  int ns = blockIdx.x, b = blockIdx.y;
  int n0 = ns*64, tid = threadIdx.x;
  for (int i = tid; i < 4096; i += 576){ int f = i >> 6, n = i & 63; u2s[f][n] = u2[f*NN + n0 + n]; }
  float S2 = sums[1];
  for (int i = tid; i < CC*TT; i += 576){
    int f = i / TT, t = i % TT;
    float acc = 0.f;
    #pragma unroll 8
    for (int nt = 0; nt < 32; ++nt) acc += pw1g[((size_t)(b*32 + nt))*CC*TT + i];
    w1s[i] = acc + S2*dt[b*CT + t*CC + f];
  }
  for (int i = tid; i < 1536; i += 576) ((float*)rh)[i] = rhs[(size_t)b*NN*TT + n0*TT + i];
  __syncthreads();
  for (int idx = tid; idx < 1536; idx += 576){
    int t = idx >> 6, n = idx & 63;
    float acc = 0.f;
    #pragma unroll 8
    for (int f = 0; f < CC; ++f) acc += u2s[f][n]*w1s[f*TT + t];
    lh[t][n] = acc;
  }
  __syncthreads();
  int t = tid / TT, s = tid % TT;
  float acc = 0.f;
  #pragma unroll 4
  for (int n = 0; n < 64; ++n) acc += lh[t][n]*rh[n][s];
  pprod[((size_t)(b*8 + ns))*576 + tid] = acc;
}

// ---------------- attention tail (att2): sum partials -> sigmoid -> ve -> softmax
__global__ void k_att_post2(const float* __restrict__ pprod, const float* __restrict__ ve,
                            const float* __restrict__ be, float* __restrict__ E){
  __shared__ float sig_s[TT*TT], E_s[TT*TT];
  int b = blockIdx.x, tid = threadIdx.x;
  float acc = 0.f;
  #pragma unroll
  for (int p = 0; p < 8; ++p) acc += pprod[((size_t)(b*8 + p))*576 + tid];
  sig_s[tid] = 1.f/(1.f + expf(-(acc + be[tid])));
  __syncthreads();
  {
    int t = tid / TT, r = tid % TT;
    float a = 0.f;
    for (int s = 0; s < TT; ++s) a += ve[t*TT + s]*sig_s[s*TT + r];
    E_s[tid] = a;
  }
  __syncthreads();
  if (tid < TT){
    int r = tid;
    float mx = -1e30f;
    for (int t = 0; t < TT; ++t) mx = fmaxf(mx, E_s[t*TT + r]);
    float sum = 0.f;
    for (int t = 0; t < TT; ++t) sum += expf(E_s[t*TT + r] - mx);
    float inv = 1.f/sum;
    for (int t = 0; t < TT; ++t) E[(size_t)b*TT*TT + t*TT + r] = expf(E_s[t*TT + r] - mx)*inv;
  }
}

// ---------------- att1 tail fused into xtat: E in LDS, never global
__global__ __launch_bounds__(256) void k_xtat(const float* __restrict__ ppr, const float* __restrict__ ve,
                       const float* __restrict__ be, const float* __restrict__ x,
                       const float* __restrict__ sw1, const float* __restrict__ sw2,
                       const float* __restrict__ sw3,
                       float* __restrict__ lx, float* __restrict__ r2){
  __shared__ float sig_s[576], E_s[576], sw1_s[TT], sw2_s[TT];
  int b = blockIdx.x >> 1, half = blockIdx.x & 1, tid = threadIdx.x;
  for (int i = tid; i < 576; i += 256){
    float acc = 0.f;
    #pragma unroll
    for (int p = 0; p < 8; ++p) acc += ppr[((size_t)(b*8 + p))*576 + i];
    sig_s[i] = 1.f/(1.f + expf(-(acc + be[i])));
  }
  if (tid < TT){ sw1_s[tid] = sw1[tid]; sw2_s[tid] = sw2[tid]; }
  __syncthreads();
  for (int i = tid; i < 576; i += 256){
    int t = i / TT, r = i % TT;
    float a = 0.f;
    for (int s = 0; s < TT; ++s) a += ve[t*TT + s]*sig_s[s*TT + r];
    E_s[i] = a;
  }
  __syncthreads();
  if (tid < TT){
    int r = tid;
    float mx = -1e30f;
    for (int t = 0; t < TT; ++t) mx = fmaxf(mx, E_s[t*TT + r]);
    float sum = 0.f;
    for (int t = 0; t < TT; ++t) sum += expf(E_s[t*TT + r] - mx);
    float inv = 1.f/sum;
    for (int t = 0; t < TT; ++t) E_s[t*TT + r] = expf(E_s[t*TT + r] - mx)*inv;
  }
  __syncthreads();
  int n = half*256 + tid;
  float xr[TT];
  const float* xp = x + (size_t)(b*NN + n)*TT;
  for (int t = 0; t < TT; ++t) xr[t] = xp[t];
  float l = 0.f, r = 0.f;
  for (int s = 0; s < TT; ++s){
    float acc = 0.f;
    for (int t = 0; t < TT; ++t) acc += xr[t]*E_s[t*TT + s];
    l += acc*sw1_s[s];
    r += acc*sw2_s[s];
  }
  lx[b*NN + n] = l;
  r2[b*NN + n] = r*sw3[0];
}

// ---------------- Qb[b][k][m] = bf16(sigmoid(lx[m]*r2[k] + sbT[k][m]))
__global__ __launch_bounds__(256) void k_sig(const float* __restrict__ lx, const float* __restrict__ r2,
                     const float* __restrict__ sbT, short* __restrict__ Qb){
  int b = blockIdx.y;
  int k = blockIdx.x*4 + (threadIdx.x >> 6);
  int m8 = (threadIdx.x & 63)*8;
  float r2k = r2[b*NN + k];
  const float* lxb = lx + b*NN;
  float4 l0 = *(const float4*)(lxb + m8);
  float4 l1 = *(const float4*)(lxb + m8 + 4);
  const float* sb = sbT + (size_t)k*NN + m8;
  float4 s0 = *(const float4*)(sb);
  float4 s1 = *(const float4*)(sb + 4);
  bf16x8 o;
  o[0] = f2bf(1.f/(1.f + __expf(-(l0.x*r2k + s0.x))));
  o[1] = f2bf(1.f/(1.f + __expf(-(l0.y*r2k + s0.y))));
  o[2] = f2bf(1.f/(1.f + __expf(-(l0.z*r2k + s0.z))));
  o[3] = f2bf(1.f/(1.f + __expf(-(l0.w*r2k + s0.w))));
  o[4] = f2bf(1.f/(1.f + __expf(-(l1.x*r2k + s1.x))));
  o[5] = f2bf(1.f/(1.f + __expf(-(l1.y*r2k + s1.y))));
  o[6] = f2bf(1.f/(1.f + __expf(-(l1.z*r2k + s1.z))));
  o[7] = f2bf(1.f/(1.f + __expf(-(l1.w*r2k + s1.w))));
  *(bf16x8*)(Qb + ((size_t)b*NN + k)*NN + m8) = o;
}

// ---------------- ST[b][k][n] = sum_m svB[n][m] * Qb[b][k][m]  (MFMA, BK=64 + XOR swizzle)
__global__ __launch_bounds__(256) void k_S0(const __hip_bfloat16* __restrict__ svB,
                    const short* __restrict__ Qb, float* __restrict__ ST){
  __shared__ __align__(16) short lA[128*64];
  __shared__ __align__(16) short lB[128*64];
  int kt = blockIdx.x, nt = blockIdx.y, b = blockIdx.z;
  int n0 = nt*128, k0 = kt*128;
  int tid = threadIdx.x;
  int w = tid >> 6, l = tid & 63;
  int wr = w >> 1, wc = w & 1;
  int lrow = l & 15, lk = l >> 4;
  int srow = l >> 3;
  int scol = ((l & 7) ^ srow)*8;
  int swz = (lrow & 7) << 3;
  f32x4 acc[4][4];
  #pragma unroll
  for (int m = 0; m < 4; ++m)
    #pragma unroll
    for (int n = 0; n < 4; ++n) acc[m][n] = (f32x4){0.f,0.f,0.f,0.f};
  for (int mk = 0; mk < NN; mk += 64){
    #pragma unroll
    for (int p = 0; p < 4; ++p){
      int c = p*4 + w;
      __builtin_amdgcn_global_load_lds(
        (const __attribute__((address_space(1))) void*)(svB + (size_t)(n0 + c*8 + srow)*NN + mk + scol),
        (__attribute__((address_space(3))) void*)(lA + c*512), 16, 0, 0);
      __builtin_amdgcn_global_load_lds(
        (const __attribute__((address_space(1))) void*)(Qb + ((size_t)b*NN + k0 + c*8 + srow)*NN + mk + scol),
        (__attribute__((address_space(3))) void*)(lB + c*512), 16, 0, 0);
    }
    __syncthreads();
    #pragma unroll
    for (int h = 0; h < 2; ++h){
      bf16x8 a[4], bv[4];
      #pragma unroll
      for (int m = 0; m < 4; ++m){
        int row = wr*64 + m*16 + lrow;
        a[m] = *(const bf16x8*)(lA + row*64 + ((h*32 + lk*8) ^ swz));
      }
      #pragma unroll
      for (int n = 0; n < 4; ++n){
        int row = wc*64 + n*16 + lrow;
        bv[n] = *(const bf16x8*)(lB + row*64 + ((h*32 + lk*8) ^ swz));
      }
      #pragma unroll
      for (int m = 0; m < 4; ++m)
        #pragma unroll
        for (int n = 0; n < 4; ++n)
          acc[m][n] = __builtin_amdgcn_mfma_f32_16x16x32_bf16(a[m], bv[n], acc[m][n], 0, 0, 0);
    }
    __syncthreads();
  }
  #pragma unroll
  for (int m = 0; m < 4; ++m){
    #pragma unroll
    for (int n = 0; n < 4; ++n){
      int col = k0 + wc*64 + n*16 + lrow;
      int row = n0 + wr*64 + m*16 + lk*4;
      float4 v; v.x = acc[m][n][0]; v.y = acc[m][n][1]; v.z = acc[m][n][2]; v.w = acc[m][n][3];
      *(float4*)(ST + (size_t)b*NN*NN + (size_t)col*NN + row) = v;
    }
  }
}

// ---------------- row softmax of ST -> P bf16 (unnormalized exp) + invZ
__global__ __launch_bounds__(256) void k_expS(const float* __restrict__ ST, short* __restrict__ P,
                      float* __restrict__ invZ){
  int b = blockIdx.y;
  int row = blockIdx.x*4 + (threadIdx.x >> 6);
  int l = threadIdx.x & 63;
  const float* R = ST + (size_t)b*NN*NN + (size_t)row*NN;
  float4 v0 = *(const float4*)(R + l*8);
  float4 v1 = *(const float4*)(R + l*8 + 4);
  float mx = fmaxf(fmaxf(fmaxf(v0.x,v0.y),fmaxf(v0.z,v0.w)),
                   fmaxf(fmaxf(v1.x,v1.y),fmaxf(v1.z,v1.w)));
  for (int off = 32; off; off >>= 1) mx = fmaxf(mx, __shfl_xor(mx, off));
  v0.x = __expf(v0.x-mx); v0.y = __expf(v0.y-mx); v0.z = __expf(v0.z-mx); v0.w = __expf(v0.w-mx);
  v1.x = __expf(v1.x-mx); v1.y = __expf(v1.y-mx); v1.z = __expf(v1.z-mx); v1.w = __expf(v1.w-mx);
  float s = v0.x+v0.y+v0.z+v0.w+v1.x+v1.y+v1.z+v1.w;
  for (int off = 32; off; off >>= 1) s += __shfl_xor(s, off);
  bf16x8 o;
  o[0]=f2bf(v0.x); o[1]=f2bf(v0.y); o[2]=f2bf(v0.z); o[3]=f2bf(v0.w);
  o[4]=f2bf(v1.x); o[5]=f2bf(v1.y); o[6]=f2bf(v1.z); o[7]=f2bf(v1.w);
  *(bf16x8*)(P + ((size_t)b*NN + row)*NN + l*8) = o;
  if (l == 0) invZ[b*NN + row] = 1.f/s;
}

// ---------------- tmp_kc[b] = (P[b] .* chebT[kc]) @ xT[b]^T (MFMA, BK=64 + XOR swizzle)
__global__ __launch_bounds__(256) void k_tmpG(const short* __restrict__ P, const short* __restrict__ chebT,
                      const short* __restrict__ xT, const float* __restrict__ invZ,
                      float* __restrict__ tmp){
  __shared__ __align__(16) short lP[128*64];
  __shared__ __align__(16) short lC[128*64];
  __shared__ __align__(16) short lX[32*64];
  __shared__ float iz_s[128];
  int it = blockIdx.x, kc = blockIdx.y, b = blockIdx.z;
  int i0 = it*128;
  int tid = threadIdx.x;
  int w = tid >> 6, l = tid & 63;
  int lrow = l & 15, lk = l >> 4;
  int srow = l >> 3;
  int scol = ((l & 7) ^ srow)*8;
  int swz = (lrow & 7) << 3;
  if (tid < 128) iz_s[tid] = invZ[b*NN + i0 + tid];
  f32x4 acc[2][2];
  #pragma unroll
  for (int m = 0; m < 2; ++m)
    #pragma unroll
    for (int n = 0; n < 2; ++n) acc[m][n] = (f32x4){0.f,0.f,0.f,0.f};
  for (int j0 = 0; j0 < NN; j0 += 64){
    #pragma unroll
    for (int p = 0; p < 4; ++p){
      int c = p*4 + w;
      __builtin_amdgcn_global_load_lds(
        (const __attribute__((address_space(1))) void*)(P + ((size_t)b*NN + i0 + c*8 + srow)*NN + j0 + scol),
        (__attribute__((address_space(3))) void*)(lP + c*512), 16, 0, 0);
      __builtin_amdgcn_global_load_lds(
        (const __attribute__((address_space(1))) void*)(chebT + ((size_t)kc*NN + i0 + c*8 + srow)*NN + j0 + scol),
        (__attribute__((address_space(3))) void*)(lC + c*512), 16, 0, 0);
    }
    {
      int c = w;
      __builtin_amdgcn_global_load_lds(
        (const __attribute__((address_space(1))) void*)(xT + ((size_t)b*32 + c*8 + srow)*NN + j0 + scol),
        (__attribute__((address_space(3))) void*)(lX + c*512), 16, 0, 0);
    }
    __syncthreads();
    #pragma unroll
    for (int h = 0; h < 2; ++h){
      bf16x8 bv[2];
      #pragma unroll
      for (int n = 0; n < 2; ++n)
        bv[n] = *(const bf16x8*)(lX + (n*16 + lrow)*64 + ((h*32 + lk*8) ^ swz));
      #pragma unroll
      for (int m = 0; m < 2; ++m){
        int r = w*32 + m*16 + lrow;
        bf16x8 pp = *(const bf16x8*)(lP + r*64 + ((h*32 + lk*8) ^ swz));
        bf16x8 cc = *(const bf16x8*)(lC + r*64 + ((h*32 + lk*8) ^ swz));
        bf16x8 af;
        #pragma unroll
        for (int e = 0; e < 8; ++e) af[e] = f2bf(bf2f(pp[e])*bf2f(cc[e]));
        #pragma unroll
        for (int n = 0; n < 2; ++n)
          acc[m][n] = __builtin_amdgcn_mfma_f32_16x16x32_bf16(af, bv[n], acc[m][n], 0, 0, 0);
      }
    }
    __syncthreads();
  }
  #pragma unroll
  for (int m = 0; m < 2; ++m){
    #pragma unroll
    for (int n = 0; n < 2; ++n){
      int t = n*16 + lrow;
      if (t < TT){
        #pragma unroll
        for (int j = 0; j < 4; ++j){
          int ir = w*32 + m*16 + lk*4 + j;
          tmp[((size_t)(kc*BB + b)*NN + i0 + ir)*TT + t] = acc[m][n][j]*iz_s[ir];
        }
      }
    }
  }
}

// ---------------- att2: per-16-n-tile two-pass: rhsg + partial w1g
__global__ __launch_bounds__(384) void k_gsum(const float* __restrict__ tmp, const float* __restrict__ theta,
                      const float* __restrict__ u1b, const float* __restrict__ u3b,
                      const float* __restrict__ du3b,
                      float* __restrict__ rhsg, float* __restrict__ pw1g){
  __shared__ float A0[16*TT], A1[16*TT], A2[16*TT], th_s[192], u3_s[CC], u1_s[16], du_s[TT];
  int nt = blockIdx.x, b = blockIdx.y;
  int n0 = nt*16, tid = threadIdx.x;
  for (int i = tid; i < 192; i += 384) th_s[i] = theta[i];
  if (tid < CC) u3_s[tid] = u3b[tid];
  if (tid < 16) u1_s[tid] = u1b[n0 + tid];
  if (tid < TT) du_s[tid] = du3b[b*TT + tid];
  A0[tid] = tmp[((size_t)(0*BB + b)*NN + n0)*TT + tid];
  A1[tid] = tmp[((size_t)(1*BB + b)*NN + n0)*TT + tid];
  A2[tid] = tmp[((size_t)(2*BB + b)*NN + n0)*TT + tid];
  __syncthreads();
  {
    int nn = tid / TT, t = tid % TT;
    float a0 = A0[nn*TT + t], a1 = A1[nn*TT + t], a2 = A2[nn*TT + t];
    float acc = du_s[t];
    #pragma unroll 8
    for (int f = 0; f < CC; ++f){
      float v = th_s[f]*a0 + th_s[64 + f]*a1 + th_s[128 + f]*a2;
      acc += u3_s[f]*fmaxf(v, 0.f);
    }
    rhsg[(size_t)b*NN*TT + (n0 + nn)*TT + t] = acc;
  }
  #pragma unroll
  for (int p = 0; p < 4; ++p){
    int o = tid + p*384;
    int f = o / TT, t = o % TT;
    float t0 = th_s[f], t1 = th_s[64 + f], t2 = th_s[128 + f];
    float acc = 0.f;
    #pragma unroll
    for (int m = 0; m < 16; ++m){
      float v = t0*A0[m*TT + t] + t1*A1[m*TT + t] + t2*A2[m*TT + t];
      acc += u1_s[m]*fmaxf(v, 0.f);
    }
    pw1g[((size_t)(b*32 + nt))*CC*TT + o] = acc;
  }
}

// ---------------- g2 (bf16) = relu(theta·tmp) @ E2 — register-accumulated, broadcast E reads
__global__ __launch_bounds__(256) void k_g2(const float* __restrict__ tmp, const float* __restrict__ E2,
                     const float* __restrict__ theta, __hip_bfloat16* __restrict__ g2){
  __shared__ float E_s[TT*TT], th_s[192], tr[3*4*TT];
  __shared__ float g_s[256*25];   // [nn*64+f][s], pad 24->25
  int b = blockIdx.y, n0 = blockIdx.x*4, tid = threadIdx.x;
  for (int i = tid; i < 576; i += 256) E_s[i] = E2[(size_t)b*576 + i];
  for (int i = tid; i < 192; i += 256) th_s[i] = theta[i];
  for (int i = tid; i < 288; i += 256){
    int k = i / 96, rem = i % 96, nn = rem / TT, s = rem % TT;
    tr[i] = tmp[((size_t)(k*BB + b)*NN + n0 + nn)*TT + s];
  }
  __syncthreads();
  for (int idx = tid; idx < 4*CC*TT; idx += 256){
    int nn = idx / (CC*TT), rem = idx % (CC*TT), f = rem / TT, s = rem % TT;
    float v = th_s[f]*tr[nn*TT + s] + th_s[64 + f]*tr[96 + nn*TT + s] + th_s[128 + f]*tr[192 + nn*TT + s];
    g_s[(nn*64 + f)*25 + s] = fmaxf(v, 0.f);
  }
  __syncthreads();
  const float* gr = g_s + tid*25;
  float acc[TT];
  #pragma unroll
  for (int t = 0; t < TT; ++t) acc[t] = 0.f;
  #pragma unroll
  for (int s = 0; s < TT; ++s){
    float gs = gr[s];
    const float* er = E_s + s*TT;
    #pragma unroll
    for (int t = 0; t < TT; ++t) acc[t] += gs*er[t];
  }
  int nn = tid >> 6, f = tid & 63;
  __hip_bfloat16* go = g2 + (size_t)(b*NN + n0 + nn)*CT + f*TT;
  #pragma unroll
  for (int q = 0; q < 3; ++q){
    bf16x8 o;
    #pragma unroll
    for (int e = 0; e < 8; ++e) o[e] = f2bf(acc[q*8 + e]);
    *(bf16x8*)((short*)go + q*8) = o;
  }
}

// ---------------- tlin(bf16) = A @ W^T + l1_b — BK=64, XOR-swizzled LDS, XCD-swizzled grid
__global__ __launch_bounds__(256) void k_gemm_bf16(const __hip_bfloat16* __restrict__ A,
                      const __hip_bfloat16* __restrict__ W,
                      const float* __restrict__ bias, __hip_bfloat16* __restrict__ Cout){
  int bid = blockIdx.x;
  int nb = (bid & 7)*192 + (bid >> 3);
  int o0 = (nb % 12)*128, i0 = (nb / 12)*128;
  __shared__ __align__(16) short lA[128*64];
  __shared__ __align__(16) short lB[128*64];
  int tid = threadIdx.x;
  int w = tid >> 6, l = tid & 63;
  int wr = w >> 1, wc = w & 1;
  int lrow = l & 15, lk = l >> 4;
  int srow = l >> 3;
  int scol = ((l & 7) ^ srow)*8;
  int swz = (lrow & 7) << 3;
  f32x4 acc[4][4];
  #pragma unroll
  for (int m = 0; m < 4; ++m)
    #pragma unroll
    for (int n = 0; n < 4; ++n) acc[m][n] = (f32x4){0.f,0.f,0.f,0.f};
  for (int k0 = 0; k0 < CT; k0 += 64){
    #pragma unroll
    for (int p = 0; p < 4; ++p){
      int c = p*4 + w;
      __builtin_amdgcn_global_load_lds(
        (const __attribute__((address_space(1))) void*)(A + (size_t)(i0 + c*8 + srow)*CT + k0 + scol),
        (__attribute__((address_space(3))) void*)(lA + c*512), 16, 0, 0);
      __builtin_amdgcn_global_load_lds(
        (const __attribute__((address_space(1))) void*)(W + (size_t)(o0 + c*8 + srow)*CT + k0 + scol),
        (__attribute__((address_space(3))) void*)(lB + c*512), 16, 0, 0);
    }
    __syncthreads();
    #pragma unroll
    for (int h = 0; h < 2; ++h){
      bf16x8 a[4], bv[4];
      #pragma unroll
      for (int m = 0; m < 4; ++m){
        int row = wr*64 + m*16 + lrow;
        a[m] = *(const bf16x8*)(lA + row*64 + ((h*32 + lk*8) ^ swz));
      }
      #pragma unroll
      for (int n = 0; n < 4; ++n){
        int row = wc*64 + n*16 + lrow;
        bv[n] = *(const bf16x8*)(lB + row*64 + ((h*32 + lk*8) ^ swz));
      }
      #pragma unroll
      for (int m = 0; m < 4; ++m)
        #pragma unroll
        for (int n = 0; n < 4; ++n)
          acc[m][n] = __builtin_amdgcn_mfma_f32_16x16x32_bf16(a[m], bv[n], acc[m][n], 0, 0, 0);
    }
    __syncthreads();
  }
  #pragma unroll
  for (int m = 0; m < 4; ++m){
    #pragma unroll
    for (int n = 0; n < 4; ++n){
      int o = o0 + wc*64 + n*16 + lrow;
      float bo = bias[o];
      #pragma unroll
      for (int j = 0; j < 4; ++j){
        int i = i0 + wr*64 + m*16 + lk*4 + j;
        Cout[(size_t)i*CT + o] = __float2bfloat16(acc[m][n][j] + bo);
      }
    }
  }
}

// ---------------- reshape + residual + relu + LayerNorm (LDS-staged, bf16 tlin)
__global__ __launch_bounds__(128) void k_final(const __hip_bfloat16* __restrict__ tlin, const float* __restrict__ x,
                      const float* __restrict__ res_w, const float* __restrict__ res_b,
                      const float* __restrict__ ln_g, const float* __restrict__ ln_b,
                      float* __restrict__ out){
  __shared__ float Ls[64][132];
  __shared__ float rw_s[64], rb_s[64], lg_s[64], lb_s[64];
  int ot = blockIdx.x, dlt = blockIdx.y, b = blockIdx.z;
  int o0 = ot*128, tid = threadIdx.x;
  if (tid < 64){ rw_s[tid]=res_w[tid]; rb_s[tid]=res_b[tid]; lg_s[tid]=ln_g[tid]; lb_s[tid]=ln_b[tid]; }
  const __hip_bfloat16* tb = tlin + (size_t)b*NN*CT;
  #pragma unroll 4
  for (int c = 0; c < 64; ++c)
    Ls[c][tid] = __bfloat162float(tb[(size_t)(c*8 + dlt)*CT + o0 + tid]);
  __syncthreads();
  int p = dlt*CT + o0 + tid;
  int np = p / TT, tp = p % TT;
  float xv = x[(size_t)(b*NN + np)*TT + tp];
  float z[CC];
  float sum = 0.f, sq = 0.f;
  #pragma unroll
  for (int c = 0; c < CC; ++c){
    float v = Ls[c][tid] + xv*rw_s[c] + rb_s[c];
    v = fmaxf(v, 0.f);
    z[c] = v; sum += v; sq += v*v;
  }
  float mu = sum*(1.f/64.f);
  float var = sq*(1.f/64.f) - mu*mu;
  float rstd = rsqrtf(var + 1e-5f);
  float* ob = out + (size_t)(b*NN + np)*CC*TT + tp;
  #pragma unroll
  for (int c = 0; c < CC; ++c)
    ob[c*TT] = (z[c] - mu)*rstd*lg_s[c] + lb_s[c];
}

extern "C" void kernel_launch(void* const* d_in, const int* in_sizes, int n_in,
                              void* d_out, int out_size, void* d_ws, size_t ws_size,
                              hipStream_t stream){
  const float* x    = (const float*)d_in[0];
  const float* y    = (const float*)d_in[1];
  const float* tl_w = (const float*)d_in[2];
  const float* tl_b = (const float*)d_in[3];
  const float* u0_w = (const float*)d_in[4];
  const float* u0_b = (const float*)d_in[5];
  const float* u1a  = (const float*)d_in[6];
  const float* u2a  = (const float*)d_in[7];
  const float* u3a  = (const float*)d_in[8];
  const float* be_a = (const float*)d_in[9];
  const float* ve_a = (const float*)d_in[10];
  const float* u1b  = (const float*)d_in[11];
  const float* u2b  = (const float*)d_in[12];
  const float* u3b  = (const float*)d_in[13];
  const float* be_b = (const float*)d_in[14];
  const float* ve_b = (const float*)d_in[15];
  const float* sw1  = (const float*)d_in[16];
  const float* sw2  = (const float*)d_in[17];
  const float* sw3  = (const float*)d_in[18];
  const float* s_bs = (const float*)d_in[19];
  const float* s_vs = (const float*)d_in[20];
  const float* cheb = (const float*)d_in[21];
  const float* theta= (const float*)d_in[22];
  const float* l1_w = (const float*)d_in[23];
  const float* l1_b = (const float*)d_in[24];
  const float* res_w= (const float*)d_in[25];
  const float* res_b= (const float*)d_in[26];
  const float* ln_g = (const float*)d_in[27];
  const float* ln_b = (const float*)d_in[28];
  float* out = (float*)d_out;
  float* ws  = (float*)d_ws;

  // ws layout (floats). big regions & lifetimes (verified, as R17):
  //  [0, 3.79M): WB/yB/pdt (k_pre -> k_small)        [0, 8.39M): ST (k_S0 -> k_expS)
  //  [8.39M, 12.58M): Pb (k_expS -> k_tmpG)          [12.58M, 13.25M): xTb/iZ/chT (k_pre -> k_tmpG)
  //  [13.25M, 14.43M): Wb bf16 (k_pre -> k_gemm)     [14.43M, 18.63M): Qb (k_sig -> k_S0)
  //  [18.63M, 18.89M): sbT (k_pre -> k_sig)
  //  pw1g [0, 1.57M) (k_gsum -> k_prodB, after ST dead); tlin bf16 [0, 12.58M) (k_gemm -> k_final).
  float* dt   = ws;               // 49152
  float* E    = dt   + 49152;     // 18432 (E2)
  float* lxp  = E    + 18432;     // 16384
  float* r2p  = lxp  + 16384;     // 16384
  float* w0u3 = r2p  + 16384;     // 640
  float* b0u3 = w0u3 + 640;       // 64
  float* sums = b0u3 + 64;        // 64
  float* du3a = sums + 64;        // 768
  float* du3b = du3a + 768;       // 768
  float* w1a  = du3b + 768;       // 49152
  float* w1g  = w1a  + 49152;     // 49152 (unused)
  float* lhs1 = w1g  + 49152;     // 393216 (unused)
  float* rhs1 = lhs1 + 393216;    // 393216 (unused)
  float* lhsg = rhs1 + 393216;    // 393216 (unused)
  float* rhsg = lhsg + 393216;    // 393216
  float* svBf = rhsg + 393216;    // 131072 (bf16 512x512)
  float* ppr  = svBf + 131072;    // 147456
  float* tmp  = ppr  + 147456;    // 1179648
  float* big  = tmp  + 1179648;   // 25165824 floats
  float* ST   = big;
  float* pw1g = big;
  __hip_bfloat16* tlin = (__hip_bfloat16*)big;
  __hip_bfloat16* WB = (__hip_bfloat16*)big;
  __hip_bfloat16* yB = (__hip_bfloat16*)(big + 2801664);
  float* pdt = big + 2801664 + 58368;
  short* Pb  = (short*)(big + 8388608);
  short* xTb = (short*)(big + 12582912);
  float* iZ  = big + 12582912 + 262144;
  short* chT = (short*)(big + 12582912 + 262144 + 16384);
  __hip_bfloat16* Wb = (__hip_bfloat16*)(big + 13254656);    // 1536x1536 bf16
  short* Qb  = (short*)(big + 14434304);                     // 32x512x512 bf16
  float* sbT = big + 18628608;                               // 512x512 fp32
  __hip_bfloat16* svB = (__hip_bfloat16*)svBf;
  __hip_bfloat16* g2b = (__hip_bfloat16*)d_out;
  (void)w1g; (void)lhs1; (void)rhs1; (void)lhsg;

  k_pre<<<dim3(6410), dim3(256), 0, stream>>>(s_vs, y, tl_w, cheb, x, l1_w, s_bs,
                                              u0_w, u0_b, u1a, u3a, u1b,
                                              svB, yB, WB, chT, xTb, Wb, sbT,
                                              w0u3, b0u3, sums);
  k_dtgemm<<<dim3(6, 19), dim3(256), 0, stream>>>(yB, WB, pdt);
  k_small<<<dim3(32), dim3(256), 0, stream>>>(x, pdt, tl_b, u0_w, u0_b, u1a, u3a, u3b, sums, dt, w1a, du3a, du3b);
  k_prodA<<<dim3(8, 32), dim3(576), 0, stream>>>(x, w0u3, b0u3, du3a, u2a, w1a, ppr);
  k_xtat<<<dim3(64), dim3(256), 0, stream>>>(ppr, ve_a, be_a, x, sw1, sw2, sw3, lxp, r2p);
  k_sig<<<dim3(128, 32), dim3(256), 0, stream>>>(lxp, r2p, sbT, Qb);
  k_S0<<<dim3(4, 4, 32), dim3(256), 0, stream>>>(svB, Qb, ST);
  k_expS<<<dim3(128, 32), dim3(256), 0, stream>>>(ST, Pb, iZ);
  k_tmpG<<<dim3(4, 3, 32), dim3(256), 0, stream>>>(Pb, chT, xTb, iZ, tmp);
  k_gsum<<<dim3(32, 32), dim3(384), 0, stream>>>(tmp, theta, u1b, u3b, du3b, rhsg, pw1g);
  k_prodB<<<dim3(8, 32), dim3(576), 0, stream>>>(u2b, pw1g, dt, sums, rhsg, ppr);
  k_att_post2<<<dim3(32), dim3(576), 0, stream>>>(ppr, ve_b, be_b, E);
  k_g2<<<dim3(128, 32), dim3(256), 0, stream>>>(tmp, E, theta, g2b);
  k_gemm_bf16<<<dim3(1536), dim3(256), 0, stream>>>(g2b, Wb, l1_b, tlin);
  k_final<<<dim3(12, 8, 32), dim3(128), 0, stream>>>(tlin, x, res_w, res_b, ln_g, ln_b, out);
}